// Round 3
// baseline (282.886 us; speedup 1.0000x reference)
//
#include <hip/hip_runtime.h>

typedef unsigned short u16;
typedef __attribute__((ext_vector_type(8))) short bf16x8;
typedef __attribute__((ext_vector_type(4))) short s16x4;
typedef __attribute__((ext_vector_type(4))) float f32x4;

__device__ __forceinline__ float bf2f(u16 u) {
  union { unsigned int i; float f; } v; v.i = ((unsigned int)u) << 16; return v.f;
}
__device__ __forceinline__ u16 f2bf(float f) {
  union { float f; unsigned int i; } v; v.f = f;
  unsigned int r = v.i + 0x7fffu + ((v.i >> 16) & 1u);
  return (u16)(r >> 16);
}
__device__ __forceinline__ f32x4 MFMA(bf16x8 a, bf16x8 b, f32x4 c) {
  return __builtin_amdgcn_mfma_f32_16x16x32_bf16(a, b, c, 0, 0, 0);
}
__device__ __forceinline__ void cvt8(const float* p, uint4* dst) {
  float4 f0 = *(const float4*)(p);
  float4 f1 = *(const float4*)(p + 4);
  u16* t = (u16*)dst;
  t[0] = f2bf(f0.x); t[1] = f2bf(f0.y); t[2] = f2bf(f0.z); t[3] = f2bf(f0.w);
  t[4] = f2bf(f1.x); t[5] = f2bf(f1.y); t[6] = f2bf(f1.z); t[7] = f2bf(f1.w);
}

// ---------------------------------------------------------------------------
// GEMM: C = A @ Bw^T + bias.  A: MxK row-major (fp32 if AF32 else bf16),
// Bw: NxK row-major fp32 (converted to bf16 during LDS staging).
// MODE 0: plain row-major fp32 C0[m*N+n]
// MODE 1: QKV scatter (bf16 planes): n -> (which, head, c); m -> (b, npos)
//   which 0 -> C0 = Q[bh][npos][c], which 1 -> C1 = K[bh][npos][c],
//   which 2 -> C2 = VT[bh][c][npos]
// ---------------------------------------------------------------------------
template<int MODE, int AF32>
__global__ __launch_bounds__(256) void gemm_bt(
    const void* __restrict__ Av, const float* __restrict__ Bw, const float* __restrict__ bias,
    void* __restrict__ C0v, u16* __restrict__ C1, u16* __restrict__ C2,
    int M, int N, int K)
{
  __shared__ u16 sA[128 * 32];
  __shared__ u16 sB[128 * 32];
  const int tid = threadIdx.x;
  const int lane = tid & 63, wv = tid >> 6;
  const int wr = wv >> 1, wc = wv & 1;
  const int l16 = lane & 15, quad = lane >> 4;
  const int m0 = blockIdx.y << 7, n0 = blockIdx.x << 7;

  const int arow = tid >> 1, acb = (tid & 1) << 4;
  const float* gAf = (const float*)Av + (size_t)(m0 + arow) * K + acb;
  const u16*   gAb = (const u16*)Av + (size_t)(m0 + arow) * K + acb;
  const float* gBf = Bw + (size_t)(n0 + arow) * K + acb;
  u16* lA = sA + tid * 16;   // linear chunk per thread: conflict-free stores
  u16* lB = sB + tid * 16;

  f32x4 acc[4][4];
  #pragma unroll
  for (int i = 0; i < 4; ++i)
    #pragma unroll
    for (int j = 0; j < 4; ++j) {
      acc[i][j][0] = 0.f; acc[i][j][1] = 0.f; acc[i][j][2] = 0.f; acc[i][j][3] = 0.f;
    }

  for (int k0 = 0; k0 < K; k0 += 32) {
    uint4 pa0, pa1, pb0, pb1;
    if (AF32) {
      cvt8(gAf + k0, &pa0);
      cvt8(gAf + k0 + 8, &pa1);
    } else {
      pa0 = *(const uint4*)(gAb + k0);
      pa1 = *(const uint4*)(gAb + k0 + 8);
    }
    cvt8(gBf + k0, &pb0);
    cvt8(gBf + k0 + 8, &pb1);
    __syncthreads();
    *(uint4*)lA = pa0; *(uint4*)(lA + 8) = pa1;
    *(uint4*)lB = pb0; *(uint4*)(lB + 8) = pb1;
    __syncthreads();
    bf16x8 af[4], bfr[4];
    #pragma unroll
    for (int i = 0; i < 4; ++i)
      af[i] = *(const bf16x8*)(sA + (wr * 64 + i * 16 + l16) * 32 + quad * 8);
    #pragma unroll
    for (int j = 0; j < 4; ++j)
      bfr[j] = *(const bf16x8*)(sB + (wc * 64 + j * 16 + l16) * 32 + quad * 8);
    #pragma unroll
    for (int i = 0; i < 4; ++i)
      #pragma unroll
      for (int j = 0; j < 4; ++j)
        acc[i][j] = MFMA(af[i], bfr[j], acc[i][j]);
  }

  #pragma unroll
  for (int j = 0; j < 4; ++j) {
    const int n = n0 + wc * 64 + j * 16 + l16;
    const float bv = bias[n];
    if (MODE == 0) {
      float* C0 = (float*)C0v;
      #pragma unroll
      for (int i = 0; i < 4; ++i) {
        const int m = m0 + wr * 64 + i * 16 + quad * 4;
        #pragma unroll
        for (int r = 0; r < 4; ++r)
          C0[(size_t)(m + r) * N + n] = acc[i][j][r] + bv;
      }
    } else {
      u16* C0 = (u16*)C0v;
      const int which = n / 768;            // uniform per 16-lane span
      const int rem = n - which * 768;
      const int head = rem >> 6, c = rem & 63;
      #pragma unroll
      for (int i = 0; i < 4; ++i) {
        const int m = m0 + wr * 64 + i * 16 + quad * 4;
        const int b = m >> 10, npos = m & 1023;
        const size_t bh = (size_t)(b * 12 + head);
        if (which == 0) {
          #pragma unroll
          for (int r = 0; r < 4; ++r)
            C0[(bh << 16) + ((size_t)(npos + r) << 6) + c] = f2bf(acc[i][j][r] + bv);
        } else if (which == 1) {
          #pragma unroll
          for (int r = 0; r < 4; ++r)
            C1[(bh << 16) + ((size_t)(npos + r) << 6) + c] = f2bf(acc[i][j][r] + bv);
        } else {
          s16x4 pk;
          #pragma unroll
          for (int r = 0; r < 4; ++r) pk[r] = (short)f2bf(acc[i][j][r] + bv);
          *(s16x4*)(C2 + (bh << 16) + ((size_t)c << 10) + npos) = pk;  // npos % 4 == 0
        }
      }
    }
  }
}

// ---------------------------------------------------------------------------
// Attention with fused decomposed rel-pos bias.
// Block = (bh, 128-q-row tile); wave w owns 32 q rows = one qh (= qt*4 + w).
// Prologue (per wave, via MFMA):
//   Sh[q][kh] = Q[q]·rph[qh+31-kh]  -> LDS (bf16), read 2/lane per k-tile
//   Sw[q][j]  = Q[q]·rpw[j]         -> LDS scratch, gathered to 16 regs/lane
// Main loop: S^T = K·Q^T via MFMA, exp (no max-sub: logits bounded),
// P packed bf16 -> LDS, O += P@V via MFMA with V^T in LDS.
// ---------------------------------------------------------------------------
__global__ __launch_bounds__(256) void attn_kernel(
    const u16* __restrict__ Q, const u16* __restrict__ Kt, const u16* __restrict__ VT,
    const float* __restrict__ rph, const float* __restrict__ rpw,
    u16* __restrict__ Oa)
{
  // Union region: phase A = rph/rpw staging, phase B = Sw scratch,
  // phase C (main loop) = sK/sVT/sP. 18432 u16 = 36864 B.
  __shared__ __align__(16) u16 uni[18432];
  __shared__ u16 sSh[4 * 32 * 36];   // bf16 Sh, stride 36 (u32-readable)
  __shared__ float sL[4][32];

  u16* const uRPH = uni;            // 63 rows x stride 72
  u16* const uRPW = uni + 4536;     // 64 rows x stride 72 (row 63 zero)
  u16* const uSw  = uni;            // 4 waves x 32 rows x stride 72
  u16* const sK   = uni;            // 64 x 72
  u16* const sVT  = uni + 4608;     // 64 x 72
  u16* const sP   = uni + 9216;     // 4 waves x 32 x 72

  const int tid = threadIdx.x;
  const int wave = tid >> 6, lane = tid & 63;
  const int l16 = lane & 15, quad = lane >> 4;
  const int bh = blockIdx.x >> 3, qt = blockIdx.x & 7;
  const int qrow0 = (qt << 7) + (wave << 5);   // this wave's first q row
  const int qh = qrow0 >> 5;                   // = qt*4 + wave

  // ---- Q fragments (lane dim = l16, k = c contiguous; A- and B-operand
  //      layouts coincide) ----
  bf16x8 qf[2][2];
  #pragma unroll
  for (int nq = 0; nq < 2; ++nq) {
    const u16* qp = Q + (((size_t)bh << 10) + qrow0 + nq * 16 + l16) * 64 + quad * 8;
    qf[nq][0] = *(const bf16x8*)(qp);
    qf[nq][1] = *(const bf16x8*)(qp + 32);
  }

  // ---- Phase A: stage rel-pos tables (fp32 -> bf16) ----
  for (int j = tid; j < 64 * 8; j += 256) {
    const int row = j >> 3, ck = (j & 7) << 3;
    uint4 vw;
    if (row < 63) cvt8(rpw + (size_t)row * 64 + ck, &vw);
    else { vw.x = 0u; vw.y = 0u; vw.z = 0u; vw.w = 0u; }
    *(uint4*)(uRPW + row * 72 + ck) = vw;
    if (row < 63) {
      uint4 vh;
      cvt8(rph + (size_t)row * 64 + ck, &vh);
      *(uint4*)(uRPH + row * 72 + ck) = vh;
    }
  }
  __syncthreads();

  // ---- Sh via MFMA: A=Q (m=q), B=rph[qh+31-kh] (n=kh) ----
  #pragma unroll
  for (int tk = 0; tk < 2; ++tk) {
    const int kh = tk * 16 + l16;
    const u16* bp = uRPH + (qh + 31 - kh) * 72 + quad * 8;
    bf16x8 b0 = *(const bf16x8*)(bp);
    bf16x8 b1 = *(const bf16x8*)(bp + 32);
    #pragma unroll
    for (int nq = 0; nq < 2; ++nq) {
      f32x4 c; c[0] = 0.f; c[1] = 0.f; c[2] = 0.f; c[3] = 0.f;
      c = MFMA(qf[nq][0], b0, c);
      c = MFMA(qf[nq][1], b1, c);
      #pragma unroll
      for (int r = 0; r < 4; ++r)
        sSh[wave * 1152 + (nq * 16 + quad * 4 + r) * 36 + tk * 16 + l16] = f2bf(c[r]);
    }
  }

  // ---- Sw via MFMA: B=rpw[j] (n=j), frags held in regs until barrier ----
  f32x4 swc[2][4];
  #pragma unroll
  for (int tj = 0; tj < 4; ++tj) {
    const u16* bp = uRPW + (tj * 16 + l16) * 72 + quad * 8;
    bf16x8 b0 = *(const bf16x8*)(bp);
    bf16x8 b1 = *(const bf16x8*)(bp + 32);
    #pragma unroll
    for (int nq = 0; nq < 2; ++nq) {
      f32x4 c; c[0] = 0.f; c[1] = 0.f; c[2] = 0.f; c[3] = 0.f;
      c = MFMA(qf[nq][0], b0, c);
      c = MFMA(qf[nq][1], b1, c);
      swc[nq][tj] = c;
    }
  }
  __syncthreads();   // all uRPH/uRPW reads complete before uSw overwrites them

  #pragma unroll
  for (int tj = 0; tj < 4; ++tj)
    #pragma unroll
    for (int nq = 0; nq < 2; ++nq)
      #pragma unroll
      for (int r = 0; r < 4; ++r)
        uSw[wave * 2304 + (nq * 16 + quad * 4 + r) * 72 + tj * 16 + l16] =
            f2bf(swc[nq][tj][r]);

  // gather rel_w[q][kw] = Sw[q][q-kw+31] (wave-private LDS, in-order RAW)
  float rw[2][2][4];
  #pragma unroll
  for (int nq = 0; nq < 2; ++nq) {
    const int q = nq * 16 + l16;
    #pragma unroll
    for (int hi = 0; hi < 2; ++hi)
      #pragma unroll
      for (int r = 0; r < 4; ++r) {
        const int kw = hi * 16 + quad * 4 + r;
        rw[nq][hi][r] = bf2f(uSw[wave * 2304 + q * 72 + (q - kw + 31)]);
      }
  }

  // ---- main loop state ----
  f32x4 oacc[2][4];
  #pragma unroll
  for (int nq = 0; nq < 2; ++nq)
    #pragma unroll
    for (int nd = 0; nd < 4; ++nd) {
      oacc[nq][nd][0] = 0.f; oacc[nq][nd][1] = 0.f; oacc[nq][nd][2] = 0.f; oacc[nq][nd][3] = 0.f;
    }
  float lsum[2] = {0.f, 0.f};

  for (int kt = 0; kt < 16; ++kt) {
    const int kb = kt << 6;
    uint4 kreg[2], vreg[2];
    #pragma unroll
    for (int t = 0; t < 2; ++t) {
      const int j = tid + (t << 8);
      const int row = j >> 3, ck = (j & 7) << 3;
      kreg[t] = *(const uint4*)(Kt + (((size_t)bh << 10) + kb + row) * 64 + ck);
      vreg[t] = *(const uint4*)(VT + (((size_t)bh << 6) + row) * 1024 + kb + ck);
    }
    float rh[2][2];
    #pragma unroll
    for (int nq = 0; nq < 2; ++nq) {
      const unsigned int w2 =
          *(const unsigned int*)(sSh + wave * 1152 + (nq * 16 + l16) * 36 + (kt << 1));
      rh[nq][0] = bf2f((u16)(w2 & 0xffffu));
      rh[nq][1] = bf2f((u16)(w2 >> 16));
    }
    __syncthreads();   // also protects uSw gather (kt=0) / prev-iter LDS reads
    #pragma unroll
    for (int t = 0; t < 2; ++t) {
      const int j = tid + (t << 8);
      const int row = j >> 3, ck = (j & 7) << 3;
      *(uint4*)(sK + row * 72 + ck) = kreg[t];
      *(uint4*)(sVT + row * 72 + ck) = vreg[t];
    }
    __syncthreads();

    // S^T = K·Q^T  (A = K tile: m=key, B = Q: n=q)
    f32x4 sacc[4][2];
    #pragma unroll
    for (int mk = 0; mk < 4; ++mk) {
      const u16* kp = sK + (mk * 16 + l16) * 72 + quad * 8;
      bf16x8 kf0 = *(const bf16x8*)(kp);
      bf16x8 kf1 = *(const bf16x8*)(kp + 32);
      #pragma unroll
      for (int nq = 0; nq < 2; ++nq) {
        f32x4 t4; t4[0] = 0.f; t4[1] = 0.f; t4[2] = 0.f; t4[3] = 0.f;
        t4 = MFMA(kf0, qf[nq][0], t4);
        t4 = MFMA(kf1, qf[nq][1], t4);
        sacc[mk][nq] = t4;
      }
    }
    // bias + exp, pack P[q][key] (b64 writes: 4 consecutive keys per lane)
    #pragma unroll
    for (int nq = 0; nq < 2; ++nq) {
      #pragma unroll
      for (int mk = 0; mk < 4; ++mk) {
        const float rhv = rh[nq][mk >> 1];
        s16x4 pk;
        #pragma unroll
        for (int r = 0; r < 4; ++r) {
          const float s = sacc[mk][nq][r] * 0.125f + rhv + rw[nq][mk & 1][r];
          const float p = __expf(s);
          lsum[nq] += p;
          pk[r] = (short)f2bf(p);
        }
        *(s16x4*)(&sP[(wave << 11) + (wave << 8) + (nq * 16 + l16) * 72 + mk * 16 + quad * 4]) = pk;
      }
    }
    // O += P @ V  (A = P: m=q, B = V^T rows: n=d)
    const u16* pw = sP + (wave << 11) + (wave << 8);   // wave * 2304
    #pragma unroll
    for (int ks = 0; ks < 2; ++ks) {
      bf16x8 ap0 = *(const bf16x8*)(pw + (l16) * 72 + ks * 32 + quad * 8);
      bf16x8 ap1 = *(const bf16x8*)(pw + (16 + l16) * 72 + ks * 32 + quad * 8);
      #pragma unroll
      for (int nd = 0; nd < 4; ++nd) {
        bf16x8 bv = *(const bf16x8*)(sVT + (nd * 16 + l16) * 72 + ks * 32 + quad * 8);
        oacc[0][nd] = MFMA(ap0, bv, oacc[0][nd]);
        oacc[1][nd] = MFMA(ap1, bv, oacc[1][nd]);
      }
    }
  }

  // softmax denominators: lane holds partial for q = nq*16+l16; fold quads
  #pragma unroll
  for (int nq = 0; nq < 2; ++nq) {
    lsum[nq] += __shfl_xor(lsum[nq], 16);
    lsum[nq] += __shfl_xor(lsum[nq], 32);
  }
  if (lane < 16) { sL[wave][l16] = lsum[0]; sL[wave][16 + l16] = lsum[1]; }
  // same-wave LDS RAW: in-order

  const int b = bh / 12, head = bh - b * 12;
  #pragma unroll
  for (int nq = 0; nq < 2; ++nq) {
    #pragma unroll
    for (int r = 0; r < 4; ++r) {
      const int ql = nq * 16 + quad * 4 + r;
      const float linv = 1.0f / sL[wave][ql];
      const size_t base = ((size_t)(b << 10) + qrow0 + ql) * 768 + head * 64 + l16;
      #pragma unroll
      for (int nd = 0; nd < 4; ++nd)
        Oa[base + nd * 16] = f2bf(oacc[nq][nd][r] * linv);
    }
  }
}

// ---------------------------------------------------------------------------
extern "C" void kernel_launch(void* const* d_in, const int* in_sizes, int n_in,
                              void* d_out, int out_size, void* d_ws, size_t ws_size,
                              hipStream_t stream) {
  (void)in_sizes; (void)n_in; (void)out_size; (void)ws_size;
  // Reference dtypes are float32 throughout.
  const float* x      = (const float*)d_in[0];   // (8,32,32,768)
  const float* qkv_w  = (const float*)d_in[1];   // (2304,768)
  const float* qkv_b  = (const float*)d_in[2];   // (2304)
  const float* proj_w = (const float*)d_in[3];   // (768,768)
  const float* proj_b = (const float*)d_in[4];   // (768)
  const float* rph    = (const float*)d_in[5];   // (63,64)
  const float* rpw    = (const float*)d_in[6];   // (63,64)
  float* out = (float*)d_out;

  char* ws = (char*)d_ws;
  const size_t SZ = (size_t)96 * 1024 * 64;     // elems per plane (12 MB)
  u16* Qw  = (u16*)ws;                          // Q  [bh][n][c]   bf16
  u16* Kw  = Qw + SZ;                           // K  [bh][n][c]   bf16
  u16* VTw = Kw + SZ;                           // VT [bh][c][n]   bf16
  u16* Oa  = VTw + SZ;                          // attn out [b][n][dim] bf16 (48 MB total)

  gemm_bt<1, 1><<<dim3(18, 64), 256, 0, stream>>>(x, qkv_w, qkv_b, Qw, Kw, VTw, 8192, 2304, 768);
  attn_kernel<<<768, 256, 0, stream>>>(Qw, Kw, VTw, rph, rpw, Oa);
  gemm_bt<0, 0><<<dim3(6, 64), 256, 0, stream>>>(Oa, proj_w, proj_b, out, nullptr, nullptr, 8192, 768, 768);
}

// Round 4
// 251.128 us; speedup vs baseline: 1.1265x; 1.1265x over previous
//
#include <hip/hip_runtime.h>

typedef unsigned short u16;
typedef __attribute__((ext_vector_type(8))) short bf16x8;
typedef __attribute__((ext_vector_type(4))) short s16x4;
typedef __attribute__((ext_vector_type(4))) float f32x4;

__device__ __forceinline__ float bf2f(u16 u) {
  union { unsigned int i; float f; } v; v.i = ((unsigned int)u) << 16; return v.f;
}
__device__ __forceinline__ u16 f2bf(float f) {
  union { float f; unsigned int i; } v; v.f = f;
  unsigned int r = v.i + 0x7fffu + ((v.i >> 16) & 1u);
  return (u16)(r >> 16);
}
__device__ __forceinline__ f32x4 MFMA(bf16x8 a, bf16x8 b, f32x4 c) {
  return __builtin_amdgcn_mfma_f32_16x16x32_bf16(a, b, c, 0, 0, 0);
}
__device__ __forceinline__ void cvt8(const float* p, uint4* dst) {
  float4 f0 = *(const float4*)(p);
  float4 f1 = *(const float4*)(p + 4);
  u16* t = (u16*)dst;
  t[0] = f2bf(f0.x); t[1] = f2bf(f0.y); t[2] = f2bf(f0.z); t[3] = f2bf(f0.w);
  t[4] = f2bf(f1.x); t[5] = f2bf(f1.y); t[6] = f2bf(f1.z); t[7] = f2bf(f1.w);
}
// async global->LDS, 16B per lane; LDS dest = wave-uniform base + lane*16
__device__ __forceinline__ void gld16(const u16* g, u16* l) {
  __builtin_amdgcn_global_load_lds(
      (const __attribute__((address_space(1))) unsigned int*)g,
      (__attribute__((address_space(3))) unsigned int*)l, 16, 0, 0);
}

// ---------------------------------------------------------------------------
// One-shot fp32 -> bf16 cast of x, qkv_w, proj_w (grid covers all three).
// ---------------------------------------------------------------------------
#define N8_X  786432   // 8*32*32*768 / 8
#define N8_QW 221184   // 2304*768 / 8
#define N8_PW 73728    // 768*768 / 8
__global__ __launch_bounds__(256) void cast_kernel(
    const float* __restrict__ x, const float* __restrict__ qw, const float* __restrict__ pw,
    u16* __restrict__ xb, u16* __restrict__ qwb, u16* __restrict__ pwb)
{
  const int i = blockIdx.x * 256 + threadIdx.x;
  const float* s; u16* d; int off;
  if (i < N8_X)            { s = x;  d = xb;  off = i; }
  else if (i < N8_X+N8_QW) { s = qw; d = qwb; off = i - N8_X; }
  else                     { s = pw; d = pwb; off = i - (N8_X + N8_QW); }
  uint4 pk; cvt8(s + (size_t)off * 8, &pk);
  *(uint4*)(d + (size_t)off * 8) = pk;
}

// ---------------------------------------------------------------------------
// GEMM: C = A @ Bw^T + bias.  A: MxK row-major bf16, Bw: NxK row-major bf16,
// bias fp32.  Staging via global_load_lds (16B/lane, no VGPR round-trip).
// MODE 0: plain row-major fp32 C0[m*N+n]
// MODE 1: QKV scatter (bf16 planes): n -> (which, head, c); m -> (b, npos)
//   which 0 -> C0 = Q[bh][npos][c], which 1 -> C1 = K[bh][npos][c],
//   which 2 -> C2 = VT[bh][c][npos]
// ---------------------------------------------------------------------------
template<int MODE>
__global__ __launch_bounds__(256) void gemm_bt(
    const u16* __restrict__ A, const u16* __restrict__ Bw, const float* __restrict__ bias,
    void* __restrict__ C0v, u16* __restrict__ C1, u16* __restrict__ C2,
    int M, int N, int K)
{
  __shared__ u16 sA[128 * 32];   // [row][k] 64 B rows, written by DMA in lane order
  __shared__ u16 sB[128 * 32];
  const int tid = threadIdx.x;
  const int lane = tid & 63, wv = tid >> 6;
  const int wr = wv >> 1, wc = wv & 1;
  const int l16 = lane & 15, quad = lane >> 4;
  const int m0 = blockIdx.y << 7, n0 = blockIdx.x << 7;

  // staging geometry: lane covers row (tid>>2), 8-elem chunk (tid&3)*8;
  // one wave's 64 lanes cover 16 consecutive 64 B rows = 1024 B of LDS.
  const int srow = tid >> 2, scol = (tid & 3) << 3;
  const u16* gA0 = A  + (size_t)(m0 + srow) * K + scol;
  const u16* gB0 = Bw + (size_t)(n0 + srow) * K + scol;
  const u16* gA1 = gA0 + (size_t)64 * K;
  const u16* gB1 = gB0 + (size_t)64 * K;
  u16* const lwA0 = sA + wv * 512;          // rows  0..63  (this wave's 16)
  u16* const lwA1 = sA + 2048 + wv * 512;   // rows 64..127
  u16* const lwB0 = sB + wv * 512;
  u16* const lwB1 = sB + 2048 + wv * 512;

  f32x4 acc[4][4];
  #pragma unroll
  for (int i = 0; i < 4; ++i)
    #pragma unroll
    for (int j = 0; j < 4; ++j) {
      acc[i][j][0] = 0.f; acc[i][j][1] = 0.f; acc[i][j][2] = 0.f; acc[i][j][3] = 0.f;
    }

  for (int k0 = 0; k0 < K; k0 += 32) {
    __syncthreads();              // previous iteration's fragment reads done
    gld16(gA0 + k0, lwA0);
    gld16(gA1 + k0, lwA1);
    gld16(gB0 + k0, lwB0);
    gld16(gB1 + k0, lwB1);
    __syncthreads();              // compiler drains vmcnt(0) before barrier
    bf16x8 af[4], bfr[4];
    #pragma unroll
    for (int i = 0; i < 4; ++i)
      af[i] = *(const bf16x8*)(sA + (wr * 64 + i * 16 + l16) * 32 + quad * 8);
    #pragma unroll
    for (int j = 0; j < 4; ++j)
      bfr[j] = *(const bf16x8*)(sB + (wc * 64 + j * 16 + l16) * 32 + quad * 8);
    #pragma unroll
    for (int i = 0; i < 4; ++i)
      #pragma unroll
      for (int j = 0; j < 4; ++j)
        acc[i][j] = MFMA(af[i], bfr[j], acc[i][j]);
  }

  #pragma unroll
  for (int j = 0; j < 4; ++j) {
    const int n = n0 + wc * 64 + j * 16 + l16;
    const float bv = bias[n];
    if (MODE == 0) {
      float* C0 = (float*)C0v;
      #pragma unroll
      for (int i = 0; i < 4; ++i) {
        const int m = m0 + wr * 64 + i * 16 + quad * 4;
        #pragma unroll
        for (int r = 0; r < 4; ++r)
          C0[(size_t)(m + r) * N + n] = acc[i][j][r] + bv;
      }
    } else {
      u16* C0 = (u16*)C0v;
      const int which = n / 768;            // uniform per 16-lane span
      const int rem = n - which * 768;
      const int head = rem >> 6, c = rem & 63;
      #pragma unroll
      for (int i = 0; i < 4; ++i) {
        const int m = m0 + wr * 64 + i * 16 + quad * 4;
        const int b = m >> 10, npos = m & 1023;
        const size_t bh = (size_t)(b * 12 + head);
        if (which == 0) {
          #pragma unroll
          for (int r = 0; r < 4; ++r)
            C0[(bh << 16) + ((size_t)(npos + r) << 6) + c] = f2bf(acc[i][j][r] + bv);
        } else if (which == 1) {
          #pragma unroll
          for (int r = 0; r < 4; ++r)
            C1[(bh << 16) + ((size_t)(npos + r) << 6) + c] = f2bf(acc[i][j][r] + bv);
        } else {
          s16x4 pk;
          #pragma unroll
          for (int r = 0; r < 4; ++r) pk[r] = (short)f2bf(acc[i][j][r] + bv);
          *(s16x4*)(C2 + (bh << 16) + ((size_t)c << 10) + npos) = pk;  // npos % 4 == 0
        }
      }
    }
  }
}

// ---------------------------------------------------------------------------
// Attention with fused decomposed rel-pos bias (unchanged from round 3).
// ---------------------------------------------------------------------------
__global__ __launch_bounds__(256) void attn_kernel(
    const u16* __restrict__ Q, const u16* __restrict__ Kt, const u16* __restrict__ VT,
    const float* __restrict__ rph, const float* __restrict__ rpw,
    u16* __restrict__ Oa)
{
  __shared__ __align__(16) u16 uni[18432];
  __shared__ u16 sSh[4 * 32 * 36];   // bf16 Sh, stride 36 (u32-readable)
  __shared__ float sL[4][32];

  u16* const uRPH = uni;            // 63 rows x stride 72
  u16* const uRPW = uni + 4536;     // 64 rows x stride 72 (row 63 zero)
  u16* const uSw  = uni;            // 4 waves x 32 rows x stride 72
  u16* const sK   = uni;            // 64 x 72
  u16* const sVT  = uni + 4608;     // 64 x 72
  u16* const sP   = uni + 9216;     // 4 waves x 32 x 72

  const int tid = threadIdx.x;
  const int wave = tid >> 6, lane = tid & 63;
  const int l16 = lane & 15, quad = lane >> 4;
  const int bh = blockIdx.x >> 3, qt = blockIdx.x & 7;
  const int qrow0 = (qt << 7) + (wave << 5);
  const int qh = qrow0 >> 5;

  bf16x8 qf[2][2];
  #pragma unroll
  for (int nq = 0; nq < 2; ++nq) {
    const u16* qp = Q + (((size_t)bh << 10) + qrow0 + nq * 16 + l16) * 64 + quad * 8;
    qf[nq][0] = *(const bf16x8*)(qp);
    qf[nq][1] = *(const bf16x8*)(qp + 32);
  }

  for (int j = tid; j < 64 * 8; j += 256) {
    const int row = j >> 3, ck = (j & 7) << 3;
    uint4 vw;
    if (row < 63) cvt8(rpw + (size_t)row * 64 + ck, &vw);
    else { vw.x = 0u; vw.y = 0u; vw.z = 0u; vw.w = 0u; }
    *(uint4*)(uRPW + row * 72 + ck) = vw;
    if (row < 63) {
      uint4 vh;
      cvt8(rph + (size_t)row * 64 + ck, &vh);
      *(uint4*)(uRPH + row * 72 + ck) = vh;
    }
  }
  __syncthreads();

  #pragma unroll
  for (int tk = 0; tk < 2; ++tk) {
    const int kh = tk * 16 + l16;
    const u16* bp = uRPH + (qh + 31 - kh) * 72 + quad * 8;
    bf16x8 b0 = *(const bf16x8*)(bp);
    bf16x8 b1 = *(const bf16x8*)(bp + 32);
    #pragma unroll
    for (int nq = 0; nq < 2; ++nq) {
      f32x4 c; c[0] = 0.f; c[1] = 0.f; c[2] = 0.f; c[3] = 0.f;
      c = MFMA(qf[nq][0], b0, c);
      c = MFMA(qf[nq][1], b1, c);
      #pragma unroll
      for (int r = 0; r < 4; ++r)
        sSh[wave * 1152 + (nq * 16 + quad * 4 + r) * 36 + tk * 16 + l16] = f2bf(c[r]);
    }
  }

  f32x4 swc[2][4];
  #pragma unroll
  for (int tj = 0; tj < 4; ++tj) {
    const u16* bp = uRPW + (tj * 16 + l16) * 72 + quad * 8;
    bf16x8 b0 = *(const bf16x8*)(bp);
    bf16x8 b1 = *(const bf16x8*)(bp + 32);
    #pragma unroll
    for (int nq = 0; nq < 2; ++nq) {
      f32x4 c; c[0] = 0.f; c[1] = 0.f; c[2] = 0.f; c[3] = 0.f;
      c = MFMA(qf[nq][0], b0, c);
      c = MFMA(qf[nq][1], b1, c);
      swc[nq][tj] = c;
    }
  }
  __syncthreads();

  #pragma unroll
  for (int tj = 0; tj < 4; ++tj)
    #pragma unroll
    for (int nq = 0; nq < 2; ++nq)
      #pragma unroll
      for (int r = 0; r < 4; ++r)
        uSw[wave * 2304 + (nq * 16 + quad * 4 + r) * 72 + tj * 16 + l16] =
            f2bf(swc[nq][tj][r]);

  float rw[2][2][4];
  #pragma unroll
  for (int nq = 0; nq < 2; ++nq) {
    const int q = nq * 16 + l16;
    #pragma unroll
    for (int hi = 0; hi < 2; ++hi)
      #pragma unroll
      for (int r = 0; r < 4; ++r) {
        const int kw = hi * 16 + quad * 4 + r;
        rw[nq][hi][r] = bf2f(uSw[wave * 2304 + q * 72 + (q - kw + 31)]);
      }
  }

  f32x4 oacc[2][4];
  #pragma unroll
  for (int nq = 0; nq < 2; ++nq)
    #pragma unroll
    for (int nd = 0; nd < 4; ++nd) {
      oacc[nq][nd][0] = 0.f; oacc[nq][nd][1] = 0.f; oacc[nq][nd][2] = 0.f; oacc[nq][nd][3] = 0.f;
    }
  float lsum[2] = {0.f, 0.f};

  for (int kt = 0; kt < 16; ++kt) {
    const int kb = kt << 6;
    uint4 kreg[2], vreg[2];
    #pragma unroll
    for (int t = 0; t < 2; ++t) {
      const int j = tid + (t << 8);
      const int row = j >> 3, ck = (j & 7) << 3;
      kreg[t] = *(const uint4*)(Kt + (((size_t)bh << 10) + kb + row) * 64 + ck);
      vreg[t] = *(const uint4*)(VT + (((size_t)bh << 6) + row) * 1024 + kb + ck);
    }
    float rh[2][2];
    #pragma unroll
    for (int nq = 0; nq < 2; ++nq) {
      const unsigned int w2 =
          *(const unsigned int*)(sSh + wave * 1152 + (nq * 16 + l16) * 36 + (kt << 1));
      rh[nq][0] = bf2f((u16)(w2 & 0xffffu));
      rh[nq][1] = bf2f((u16)(w2 >> 16));
    }
    __syncthreads();
    #pragma unroll
    for (int t = 0; t < 2; ++t) {
      const int j = tid + (t << 8);
      const int row = j >> 3, ck = (j & 7) << 3;
      *(uint4*)(sK + row * 72 + ck) = kreg[t];
      *(uint4*)(sVT + row * 72 + ck) = vreg[t];
    }
    __syncthreads();

    f32x4 sacc[4][2];
    #pragma unroll
    for (int mk = 0; mk < 4; ++mk) {
      const u16* kp = sK + (mk * 16 + l16) * 72 + quad * 8;
      bf16x8 kf0 = *(const bf16x8*)(kp);
      bf16x8 kf1 = *(const bf16x8*)(kp + 32);
      #pragma unroll
      for (int nq = 0; nq < 2; ++nq) {
        f32x4 t4; t4[0] = 0.f; t4[1] = 0.f; t4[2] = 0.f; t4[3] = 0.f;
        t4 = MFMA(kf0, qf[nq][0], t4);
        t4 = MFMA(kf1, qf[nq][1], t4);
        sacc[mk][nq] = t4;
      }
    }
    #pragma unroll
    for (int nq = 0; nq < 2; ++nq) {
      #pragma unroll
      for (int mk = 0; mk < 4; ++mk) {
        const float rhv = rh[nq][mk >> 1];
        s16x4 pk;
        #pragma unroll
        for (int r = 0; r < 4; ++r) {
          const float s = sacc[mk][nq][r] * 0.125f + rhv + rw[nq][mk & 1][r];
          const float p = __expf(s);
          lsum[nq] += p;
          pk[r] = (short)f2bf(p);
        }
        *(s16x4*)(&sP[(wave << 11) + (wave << 8) + (nq * 16 + l16) * 72 + mk * 16 + quad * 4]) = pk;
      }
    }
    const u16* pw = sP + (wave << 11) + (wave << 8);   // wave * 2304
    #pragma unroll
    for (int ks = 0; ks < 2; ++ks) {
      bf16x8 ap0 = *(const bf16x8*)(pw + (l16) * 72 + ks * 32 + quad * 8);
      bf16x8 ap1 = *(const bf16x8*)(pw + (16 + l16) * 72 + ks * 32 + quad * 8);
      #pragma unroll
      for (int nd = 0; nd < 4; ++nd) {
        bf16x8 bv = *(const bf16x8*)(sVT + (nd * 16 + l16) * 72 + ks * 32 + quad * 8);
        oacc[0][nd] = MFMA(ap0, bv, oacc[0][nd]);
        oacc[1][nd] = MFMA(ap1, bv, oacc[1][nd]);
      }
    }
  }

  #pragma unroll
  for (int nq = 0; nq < 2; ++nq) {
    lsum[nq] += __shfl_xor(lsum[nq], 16);
    lsum[nq] += __shfl_xor(lsum[nq], 32);
  }
  if (lane < 16) { sL[wave][l16] = lsum[0]; sL[wave][16 + l16] = lsum[1]; }

  const int b = bh / 12, head = bh - b * 12;
  #pragma unroll
  for (int nq = 0; nq < 2; ++nq) {
    #pragma unroll
    for (int r = 0; r < 4; ++r) {
      const int ql = nq * 16 + quad * 4 + r;
      const float linv = 1.0f / sL[wave][ql];
      const size_t base = ((size_t)(b << 10) + qrow0 + ql) * 768 + head * 64 + l16;
      #pragma unroll
      for (int nd = 0; nd < 4; ++nd)
        Oa[base + nd * 16] = f2bf(oacc[nq][nd][r] * linv);
    }
  }
}

// ---------------------------------------------------------------------------
extern "C" void kernel_launch(void* const* d_in, const int* in_sizes, int n_in,
                              void* d_out, int out_size, void* d_ws, size_t ws_size,
                              hipStream_t stream) {
  (void)in_sizes; (void)n_in; (void)out_size; (void)ws_size;
  const float* x      = (const float*)d_in[0];   // (8,32,32,768)
  const float* qkv_w  = (const float*)d_in[1];   // (2304,768)
  const float* qkv_b  = (const float*)d_in[2];   // (2304)
  const float* proj_w = (const float*)d_in[3];   // (768,768)
  const float* proj_b = (const float*)d_in[4];   // (768)
  const float* rph    = (const float*)d_in[5];   // (63,64)
  const float* rpw    = (const float*)d_in[6];   // (63,64)
  float* out = (float*)d_out;

  char* ws = (char*)d_ws;
  const size_t SZ = (size_t)96 * 1024 * 64;     // elems per plane (12 MB)
  u16* Qw  = (u16*)ws;                          // Q  [bh][n][c]   bf16
  u16* Kw  = Qw + SZ;                           // K  [bh][n][c]   bf16
  u16* VTw = Kw + SZ;                           // VT [bh][c][n]   bf16
  u16* Xb  = VTw + SZ;                          // bf16 x; aliased as Oa after QKV GEMM
  u16* Oa  = Xb;                                //   (x dead once QKV GEMM completes)
  u16* QWb = Xb + SZ;                           // bf16 qkv_w (2304x768)
  u16* PWb = QWb + (size_t)2304 * 768;          // bf16 proj_w (768x768)  -> ~55 MB total

  cast_kernel<<<4224, 256, 0, stream>>>(x, qkv_w, proj_w, Xb, QWb, PWb);
  gemm_bt<1><<<dim3(18, 64), 256, 0, stream>>>(Xb, QWb, qkv_b, Qw, Kw, VTw, 8192, 2304, 768);
  attn_kernel<<<768, 256, 0, stream>>>(Qw, Kw, VTw, rph, rpw, Oa);
  gemm_bt<0><<<dim3(6, 64), 256, 0, stream>>>(Oa, PWb, proj_b, out, nullptr, nullptr, 8192, 768, 768);
}